// Round 10
// baseline (277.488 us; speedup 1.0000x reference)
//
#include <hip/hip_runtime.h>

typedef unsigned short u16;
typedef __attribute__((ext_vector_type(8))) short s16x8;     // 8 x bf16 frag
typedef __attribute__((ext_vector_type(4))) float floatx4;
typedef __attribute__((ext_vector_type(16))) float floatx16; // 32x32 C/D frag

// xt (per batch): [cg=16][row=66][col=66][c32=32] bf16, spatial-padded NCHW32c
// SWIZZLED: within each 64B (row,col) channel-group, 16B slot ^= (col>>1)&3
#define XT_ROWELEMS 2112                 // 66*32
#define XT_CGELEMS  139392               // 66*66*32
#define XT_PB       4460544ull           // 16*66*66*32*2 bytes per batch
// wmod (per batch): [t=9][cg=16][o512=512][c32=32] bf16  (o512 contiguous)
// SWIZZLED: within each 64B o-row, c32 index ^= ((o>>1)&3)<<3
#define WM_ELEMS    2359296ull           // 9*16*512*32 elems per batch
#define WM_PB       4718592ull           // bytes per batch

// async global->LDS DMA, 16B per lane; lds dest = wave-uniform base + lane*16
#define GLDS(gp, lp) __builtin_amdgcn_global_load_lds(                      \
    (const __attribute__((address_space(1))) void*)(gp),                    \
    (__attribute__((address_space(3))) void*)(lp), 16, 0, 0)

__device__ __forceinline__ u16 f2bf(float f) {
  union { float f; unsigned u; } x; x.f = f;
  unsigned r = x.u + 0x7fffu + ((x.u >> 16) & 1u);
  return (u16)(r >> 16);
}

// ---------------- prep unit bodies (byte-identical layouts; verified R6/R8) ----------------
__device__ __forceinline__ void transpose_unit(
    char* smraw, const float* __restrict__ fm, u16* __restrict__ xt, int ti, int tid)
{
  u16* sm16 = (u16*)smraw;                      // [x=64][ci=32] pad 40
  const int y = ti & 63, cgi = (ti >> 6) & 15, bl = ti >> 10;
  const float* src = fm + (((size_t)bl * 512 + cgi * 32) * 64 + y) * 64;
  const int x4 = (tid & 15) * 4;
#pragma unroll
  for (int it = 0; it < 2; ++it) {
    int ci = (tid >> 4) + it * 16;
    float4 v = *(const float4*)&src[(size_t)ci * 4096 + x4];   // 16B/lane coalesced
    sm16[(x4 + 0) * 40 + ci] = f2bf(v.x);
    sm16[(x4 + 1) * 40 + ci] = f2bf(v.y);
    sm16[(x4 + 2) * 40 + ci] = f2bf(v.z);
    sm16[(x4 + 3) * 40 + ci] = f2bf(v.w);
  }

  u16* cgbase = xt + (size_t)(bl * 16 + cgi) * XT_CGELEMS;
  const uint4 z = {0u, 0u, 0u, 0u};
  u16* rowb = cgbase + (size_t)(y + 1) * XT_ROWELEMS;
  if (tid < 4)              ((uint4*)rowb)[tid] = z;                  // col 0
  else if (tid < 8)         ((uint4*)(rowb + 65 * 32))[tid - 4] = z;  // col 65
  if (y == 0)  for (int i = tid; i < 264; i += 256) ((uint4*)cgbase)[i] = z;
  if (y == 63) for (int i = tid; i < 264; i += 256) ((uint4*)(cgbase + 65 * XT_ROWELEMS))[i] = z;

  __syncthreads();
  const int x = tid >> 2;
  uint4 u = *(const uint4*)&sm16[x * 40 + (tid & 3) * 8];       // one ds_read_b128
  const int col = 1 + x;
  const int slot = (tid & 3) ^ ((col >> 1) & 3);                // pre-swizzle
  ((uint4*)rowb)[col * 4 + slot] = u;
}

__device__ __forceinline__ void modulate_unit(
    char* smraw, const float* __restrict__ w, const float* __restrict__ style,
    u16* __restrict__ wm, int mi, int tid)
{
  float* sv = (float*)smraw;                    // 4608 floats
  float* red = (float*)(smraw + 18432);         // 4 floats
  const int o = mi & 511, bl = mi >> 9;
  const float gain = 0.014731391f;              // 1/sqrt(512*9)
  const float* wo = w + (size_t)o * 4608;       // flat idx = ci*9 + t
  const float* st = style + (size_t)bl * 512;
  float ss = 0.f;
#pragma unroll
  for (int j = 0; j < 5; ++j) {                 // 1152 float4 slots over 256 thr
    int s4 = j * 256 + tid;
    if (s4 < 1152) {
      float4 v = *(const float4*)&wo[s4 * 4];   // 16B/lane coalesced
      int i0 = s4 * 4;
      int c0 = i0 / 9, rem = i0 - c0 * 9;       // ci of v.x
      float sa = st[c0];
      float sb = st[c0 < 511 ? c0 + 1 : 511];   // clamp: unused when c0==511
      float w0 = v.x * gain * sa;               // rem+0 < 9 always
      float w1 = v.y * gain * (rem + 1 >= 9 ? sb : sa);
      float w2 = v.z * gain * (rem + 2 >= 9 ? sb : sa);
      float w3 = v.w * gain * (rem + 3 >= 9 ? sb : sa);
      floatx4 wv = {w0, w1, w2, w3};
      ((floatx4*)sv)[s4] = wv;                  // ds_write_b128
      ss += w0 * w0 + w1 * w1 + w2 * w2 + w3 * w3;
    }
  }
#pragma unroll
  for (int off = 32; off > 0; off >>= 1) ss += __shfl_down(ss, off, 64);
  if ((tid & 63) == 0) red[tid >> 6] = ss;
  __syncthreads();
  float sinv = rsqrtf(red[0] + red[1] + red[2] + red[3] + 1e-8f);
  const int axor = ((o >> 1) & 3) << 3;         // pre-swizzle for conv A-reads
  u16* base = wm + (size_t)bl * WM_ELEMS + (size_t)o * 32;
  const int c0 = tid * 2;                       // even -> XOR keeps pair adjacent
  const int pos = (c0 & 31) ^ axor;             // even (axor has no bit0)
#pragma unroll
  for (int t = 0; t < 9; ++t) {                 // 9 paired u32 stores
    unsigned lo = f2bf(sv[c0 * 9 + t] * sinv);
    unsigned hi = f2bf(sv[(c0 + 1) * 9 + t] * sinv);
    *(unsigned*)(base + ((size_t)(t * 16 + (c0 >> 5))) * 16384 + pos) = lo | (hi << 16);
  }
}

// ---------------- fused producer dispatch (verified; prep ~24 us, near roofline) ----------------
__global__ __launch_bounds__(256) void prep_fused(
    const float* __restrict__ fm, const float* __restrict__ w,
    const float* __restrict__ style, u16* __restrict__ xt,
    u16* __restrict__ wm, int b0)
{
  __shared__ __align__(16) char smraw[18448];
  const int bid = blockIdx.x;
  const int g = bid / 3, rrole = bid - g * 3;
  const int tid = threadIdx.x;
  if (rrole < 2) {
    const int ti0 = g * 2 + rrole;
    const int y = ti0 & 63, cgi = (ti0 >> 6) & 15, bl = ti0 >> 10;
    transpose_unit(smraw, fm + (size_t)b0 * 512 * 4096,
                   xt, (bl << 10) | (cgi << 6) | y, tid);
  } else {
    const int o = g & 511, bl = g >> 9;
    modulate_unit(smraw, w, style + (size_t)b0 * 512, wm, (bl << 9) | o, tid);
  }
}

// ---------------- conv: implicit-GEMM, 32x32x16 MFMA (R6 structure otherwise frozen) ----------------
// 256x128 C tile, 256 threads = 4 waves (2M x 2N), wave tile 128x64 = 4x2 tiles of 32x32.
// Per c32-step: 2 K16-halves x 8 MFMA = 16 x mfma_f32_32x32x16_bf16 (32768 FLOP each;
// 2382-2495 TF ceiling vs 2075 for 16x16x32 = +13-17% pipe headroom, half the instrs).
// Operand layouts: A[m=lane&31][k=(lane>>5)*8+j], B[n=lane&31][k=(lane>>5)*8+j] (AMD
// lab-notes pattern, doubled-K gfx950); C/D col=lane&31, row=(reg&3)+8*(reg>>2)+4*(lane>>5)
// (m74/m101-verified). Bank balance under existing swizzles re-derived: 16B-unit positions
// mod 8 hit exactly 8 lanes each -> zero conflicts (checkable via SQ_LDS_BANK_CONFLICT).
// Staging/barriers/grid identical to verified R6 (163 us).
__global__ __launch_bounds__(256, 2) void conv_mfma(
    const u16* __restrict__ Wmod, const u16* __restrict__ xt,
    float* __restrict__ out, int b0, int nb)
{
  const int id = blockIdx.x;
  const int bl = id % nb;                           // same batch -> same XCD (round robin)
  const int rest = id / nb;
  const int og = rest & 1, p_blk = rest >> 1;       // og: 256-row M chunk; p_blk: 128 px
  const int tid = threadIdx.x;
  const int lane = tid & 63, wave = tid >> 6;
  const int wm_off = (wave & 1) * 128, wn_off = (wave >> 1) * 64;
  const int l31 = lane & 31, h = lane >> 5;

  __shared__ __align__(16) u16 As[2][8192];         // 2 x 16 KB A k-slices (256 rows x 32)
  __shared__ __align__(16) u16 Bs[8448];            // [r4][col66][c32] = 16896 B

  const int y0 = p_blk * 2;
  const size_t xt_base = ((size_t)(bl * 16) * XT_CGELEMS) + (size_t)y0 * XT_ROWELEMS;
  const size_t w_base = (size_t)bl * WM_ELEMS + (size_t)og * (256 * 32);

  auto stage_b = [&](int cgi) {                     // 16896 B contiguous, async
    const char* g = (const char*)(xt + xt_base + (size_t)cgi * XT_CGELEMS);
    for (int r = wave; r < 16; r += 4)
      GLDS(g + r * 1024 + lane * 16, (char*)Bs + r * 1024);
    if (wave == 0 && lane < 32)                     // 512 B tail
      GLDS(g + 16384 + lane * 16, (char*)Bs + 16384);
  };
  auto stage_a = [&](int t, int cgi, int buf) {     // 16 KB contiguous, async (4 GLDS/wave)
    const char* g = (const char*)(Wmod + w_base + (size_t)(t * 16 + cgi) * 16384);
    for (int r = wave; r < 16; r += 4)
      GLDS(g + r * 1024 + lane * 16, (char*)As[buf] + r * 1024);
  };

  // A fragment offsets [mt][kh]: row = wm_off + mt*32 + l31; 16B slot = kh*2 + h,
  // swizzled by ((row>>1)&3). (global o = og*256 + row; 256 ≡ 0 mod 8 -> same XOR)
  int aoff[4][2];
#pragma unroll
  for (int mt = 0; mt < 4; ++mt) {
    int row = wm_off + mt * 32 + l31;
#pragma unroll
    for (int kh = 0; kh < 2; ++kh)
      aoff[mt][kh] = row * 32 + (((kh * 2 + h) ^ ((row >> 1) & 3)) << 3);
  }
  int pr[2], pc[2];
#pragma unroll
  for (int nt = 0; nt < 2; ++nt) {
    int p = wn_off + nt * 32 + l31;                 // 0..127
    pr[nt] = p >> 6; pc[nt] = p & 63;
  }

  floatx16 acc[4][2];
#pragma unroll
  for (int mt = 0; mt < 4; ++mt)
#pragma unroll
    for (int nt = 0; nt < 2; ++nt)
#pragma unroll
      for (int r = 0; r < 16; ++r) acc[mt][nt][r] = 0.f;

  stage_b(0);
  stage_a(0, 0, 0);
  __syncthreads();                                  // vmcnt drain -> data visible

#pragma unroll 1
  for (int cgi = 0; cgi < 16; ++cgi) {
#pragma unroll 1
    for (int t = 0; t < 9; ++t) {
      const int cur = (cgi * 9 + t) & 1, nxt = cur ^ 1;
      const bool last = (cgi == 15 && t == 8);
      const bool cgb = (t == 8 && cgi < 15);        // cg boundary
      if (!last) stage_a(t < 8 ? t + 1 : 0, t < 8 ? cgi : cgi + 1, nxt);  // async prefetch

      const int ky = t / 3, kx = t - ky * 3;
      const u16* Ab = As[cur];
#pragma unroll
      for (int kh = 0; kh < 2; ++kh) {              // two K16 halves of the c32 slice
        s16x8 afr[4], bfr[2];
#pragma unroll
        for (int nt = 0; nt < 2; ++nt) {            // B[n=lane&31][k], swizzled
          int r = pr[nt] + ky, c = pc[nt] + kx;
          bfr[nt] = *(const s16x8*)&Bs[(r * 66 + c) * 32 +
                                       (((kh * 2 + h) ^ ((c >> 1) & 3)) << 3)];
        }
#pragma unroll
        for (int mt = 0; mt < 4; ++mt)              // A[m=lane&31][k], swizzled
          afr[mt] = *(const s16x8*)&Ab[aoff[mt][kh]];
#pragma unroll
        for (int mt = 0; mt < 4; ++mt)
#pragma unroll
          for (int nt = 0; nt < 2; ++nt)
            acc[mt][nt] = __builtin_amdgcn_mfma_f32_32x32x16_bf16(
                afr[mt], bfr[nt], acc[mt][nt], 0, 0, 0);
      }

      if (cgb) {
        __syncthreads();                            // all waves done reading Bs
        stage_b(cgi + 1);                           // async restage
      }
      __syncthreads();                              // drains DMA; LDS visible
    }
  }

  // epilogue: 32x32 C/D layout col=lane&31, row=(reg&3)+8*(reg>>2)+4*(lane>>5) (m74/m101)
  float* outp = out + ((size_t)(b0 + bl) * 512 + og * 256) * 4096 + p_blk * 128;
#pragma unroll
  for (int mt = 0; mt < 4; ++mt)
#pragma unroll
    for (int nt = 0; nt < 2; ++nt) {
      int n = wn_off + nt * 32 + l31;
#pragma unroll
      for (int r = 0; r < 16; ++r) {
        int m = wm_off + mt * 32 + (r & 3) + 8 * (r >> 2) + 4 * h;
        outp[(size_t)m * 4096 + n] = acc[mt][nt][r];
      }
    }
}

// ---------------- fallback: zero-workspace direct conv (known-PASS) ----------------
__global__ __launch_bounds__(256) void conv_direct(
    const float* __restrict__ fm, const float* __restrict__ style,
    const float* __restrict__ w, float* __restrict__ out)
{
  const int o = blockIdx.x, b = blockIdx.y, tid = threadIdx.x;
  __shared__ float swm[4608];
  __shared__ float red[4];
  const float gain = 0.014731391f;
  const float* wo = w + (size_t)o * 4608;
  const float* st = style + (size_t)b * 512;
  float ss = 0.f;
#pragma unroll
  for (int j = 0; j < 18; ++j) {
    int idx = j * 256 + tid;
    float v = wo[idx] * gain * st[idx / 9];
    swm[idx] = v;
    ss += v * v;
  }
#pragma unroll
  for (int off = 32; off > 0; off >>= 1) ss += __shfl_down(ss, off, 64);
  if ((tid & 63) == 0) red[tid >> 6] = ss;
  __syncthreads();
  const float sinv = rsqrtf(red[0] + red[1] + red[2] + red[3] + 1e-8f);

  const int y = tid >> 2, x0 = (tid & 3) * 16;
  float acc[16];
#pragma unroll
  for (int i = 0; i < 16; ++i) acc[i] = 0.f;
  const float* fb = fm + (size_t)b * 512 * 4096;
  for (int ci = 0; ci < 512; ++ci) {
    const float* fc = fb + (size_t)ci * 4096;
    const float* wr = swm + ci * 9;
#pragma unroll
    for (int ky = 0; ky < 3; ++ky) {
      int yy = y + ky - 1;
      if (yy < 0 || yy > 63) continue;
      const float* frow = fc + yy * 64;
#pragma unroll
      for (int kx = 0; kx < 3; ++kx) {
        float wv = wr[ky * 3 + kx];
#pragma unroll
        for (int i = 0; i < 16; ++i) {
          int xx = x0 + i + kx - 1;
          float xv = (xx >= 0 && xx < 64) ? frow[xx] : 0.f;
          acc[i] += wv * xv;
        }
      }
    }
  }
  float* op = out + ((size_t)b * 512 + o) * 4096 + y * 64 + x0;
#pragma unroll
  for (int i = 0; i < 16; ++i) op[i] = acc[i] * sinv;
}

extern "C" void kernel_launch(void* const* d_in, const int* in_sizes, int n_in,
                              void* d_out, int out_size, void* d_ws, size_t ws_size,
                              hipStream_t stream) {
  const float* fm = (const float*)d_in[0];     // (8,512,64,64) fp32
  const float* style = (const float*)d_in[1];  // (8,512) fp32
  const float* w = (const float*)d_in[2];      // (512,512,3,3) fp32
  float* out = (float*)d_out;                  // (8,512,64,64) fp32

  if (ws_size < XT_PB + WM_PB) {               // workspace too small: direct path
    conv_direct<<<dim3(512, 8), 256, 0, stream>>>(fm, style, w, out);
    return;
  }
  int nb = 8;
  while (nb > 1 && (size_t)nb * (XT_PB + WM_PB) > ws_size) nb >>= 1;

  u16* xt = (u16*)d_ws;
  u16* wmod = (u16*)((char*)d_ws + (size_t)nb * XT_PB);

  for (int b0 = 0; b0 < 8; b0 += nb) {
    prep_fused<<<dim3(1536 * nb), 256, 0, stream>>>(fm, w, style, xt, wmod, b0);
    conv_mfma<<<dim3(64 * nb), 256, 0, stream>>>(wmod, xt, out, b0, nb);
  }
}

// Round 11
// 268.660 us; speedup vs baseline: 1.0329x; 1.0329x over previous
//
#include <hip/hip_runtime.h>

typedef unsigned short u16;
typedef __attribute__((ext_vector_type(8))) short s16x8;   // 8 x bf16 frag (verified form)
typedef __attribute__((ext_vector_type(4))) float floatx4;

// xt (per batch): [cg=16][row=66][col=66][c32=32] bf16, spatial-padded NCHW32c
// SWIZZLED: within each 64B (row,col) channel-group, 16B slot ^= (col>>1)&3
#define XT_ROWELEMS 2112                 // 66*32
#define XT_CGELEMS  139392               // 66*66*32
#define XT_PB       4460544ull           // 16*66*66*32*2 bytes per batch
// wmod (per batch): [t=9][cg=16][o512=512][c32=32] bf16  (o512 contiguous)
// SWIZZLED: within each 64B o-row, c32 index ^= ((o>>1)&3)<<3
#define WM_ELEMS    2359296ull           // 9*16*512*32 elems per batch
#define WM_PB       4718592ull           // bytes per batch

// async global->LDS DMA, 16B per lane; lds dest = wave-uniform base + lane*16
#define GLDS(gp, lp) __builtin_amdgcn_global_load_lds(                      \
    (const __attribute__((address_space(1))) void*)(gp),                    \
    (__attribute__((address_space(3))) void*)(lp), 16, 0, 0)

// counted vmcnt (memory clobber: LDS reads cannot hoist above)
#define WAITVM(N) asm volatile("s_waitcnt vmcnt(" #N ")" ::: "memory")

__device__ __forceinline__ u16 f2bf(float f) {
  union { float f; unsigned u; } x; x.f = f;
  unsigned r = x.u + 0x7fffu + ((x.u >> 16) & 1u);
  return (u16)(r >> 16);
}

// ---------------- prep unit bodies (byte-identical layouts; verified R6-R10) ----------------
__device__ __forceinline__ void transpose_unit(
    char* smraw, const float* __restrict__ fm, u16* __restrict__ xt, int ti, int tid)
{
  u16* sm16 = (u16*)smraw;                      // [x=64][ci=32] pad 40
  const int y = ti & 63, cgi = (ti >> 6) & 15, bl = ti >> 10;
  const float* src = fm + (((size_t)bl * 512 + cgi * 32) * 64 + y) * 64;
  const int x4 = (tid & 15) * 4;
#pragma unroll
  for (int it = 0; it < 2; ++it) {
    int ci = (tid >> 4) + it * 16;
    float4 v = *(const float4*)&src[(size_t)ci * 4096 + x4];   // 16B/lane coalesced
    sm16[(x4 + 0) * 40 + ci] = f2bf(v.x);
    sm16[(x4 + 1) * 40 + ci] = f2bf(v.y);
    sm16[(x4 + 2) * 40 + ci] = f2bf(v.z);
    sm16[(x4 + 3) * 40 + ci] = f2bf(v.w);
  }

  u16* cgbase = xt + (size_t)(bl * 16 + cgi) * XT_CGELEMS;
  const uint4 z = {0u, 0u, 0u, 0u};
  u16* rowb = cgbase + (size_t)(y + 1) * XT_ROWELEMS;
  if (tid < 4)              ((uint4*)rowb)[tid] = z;                  // col 0
  else if (tid < 8)         ((uint4*)(rowb + 65 * 32))[tid - 4] = z;  // col 65
  if (y == 0)  for (int i = tid; i < 264; i += 256) ((uint4*)cgbase)[i] = z;
  if (y == 63) for (int i = tid; i < 264; i += 256) ((uint4*)(cgbase + 65 * XT_ROWELEMS))[i] = z;

  __syncthreads();
  const int x = tid >> 2;
  uint4 u = *(const uint4*)&sm16[x * 40 + (tid & 3) * 8];       // one ds_read_b128
  const int col = 1 + x;
  const int slot = (tid & 3) ^ ((col >> 1) & 3);                // pre-swizzle
  ((uint4*)rowb)[col * 4 + slot] = u;
}

__device__ __forceinline__ void modulate_unit(
    char* smraw, const float* __restrict__ w, const float* __restrict__ style,
    u16* __restrict__ wm, int mi, int tid)
{
  float* sv = (float*)smraw;                    // 4608 floats
  float* red = (float*)(smraw + 18432);         // 4 floats
  const int o = mi & 511, bl = mi >> 9;
  const float gain = 0.014731391f;              // 1/sqrt(512*9)
  const float* wo = w + (size_t)o * 4608;       // flat idx = ci*9 + t
  const float* st = style + (size_t)bl * 512;
  float ss = 0.f;
#pragma unroll
  for (int j = 0; j < 5; ++j) {                 // 1152 float4 slots over 256 thr
    int s4 = j * 256 + tid;
    if (s4 < 1152) {
      float4 v = *(const float4*)&wo[s4 * 4];   // 16B/lane coalesced
      int i0 = s4 * 4;
      int c0 = i0 / 9, rem = i0 - c0 * 9;       // ci of v.x
      float sa = st[c0];
      float sb = st[c0 < 511 ? c0 + 1 : 511];   // clamp: unused when c0==511
      float w0 = v.x * gain * sa;               // rem+0 < 9 always
      float w1 = v.y * gain * (rem + 1 >= 9 ? sb : sa);
      float w2 = v.z * gain * (rem + 2 >= 9 ? sb : sa);
      float w3 = v.w * gain * (rem + 3 >= 9 ? sb : sa);
      floatx4 wv = {w0, w1, w2, w3};
      ((floatx4*)sv)[s4] = wv;                  // ds_write_b128
      ss += w0 * w0 + w1 * w1 + w2 * w2 + w3 * w3;
    }
  }
#pragma unroll
  for (int off = 32; off > 0; off >>= 1) ss += __shfl_down(ss, off, 64);
  if ((tid & 63) == 0) red[tid >> 6] = ss;
  __syncthreads();
  float sinv = rsqrtf(red[0] + red[1] + red[2] + red[3] + 1e-8f);
  const int axor = ((o >> 1) & 3) << 3;         // pre-swizzle for conv A-reads
  u16* base = wm + (size_t)bl * WM_ELEMS + (size_t)o * 32;
  const int c0 = tid * 2;                       // even -> XOR keeps pair adjacent
  const int pos = (c0 & 31) ^ axor;             // even (axor has no bit0)
#pragma unroll
  for (int t = 0; t < 9; ++t) {                 // 9 paired u32 stores
    unsigned lo = f2bf(sv[c0 * 9 + t] * sinv);
    unsigned hi = f2bf(sv[(c0 + 1) * 9 + t] * sinv);
    *(unsigned*)(base + ((size_t)(t * 16 + (c0 >> 5))) * 16384 + pos) = lo | (hi << 16);
  }
}

// ---------------- fused producer dispatch (verified; prep ~24 us, near roofline) ----------------
__global__ __launch_bounds__(256) void prep_fused(
    const float* __restrict__ fm, const float* __restrict__ w,
    const float* __restrict__ style, u16* __restrict__ xt,
    u16* __restrict__ wm, int b0)
{
  __shared__ __align__(16) char smraw[18448];
  const int bid = blockIdx.x;
  const int g = bid / 3, rrole = bid - g * 3;
  const int tid = threadIdx.x;
  if (rrole < 2) {
    const int ti0 = g * 2 + rrole;
    const int y = ti0 & 63, cgi = (ti0 >> 6) & 15, bl = ti0 >> 10;
    transpose_unit(smraw, fm + (size_t)b0 * 512 * 4096,
                   xt, (bl << 10) | (cgi << 6) | y, tid);
  } else {
    const int o = g & 511, bl = g >> 9;
    modulate_unit(smraw, w, style + (size_t)b0 * 512, wm, (bl << 9) | o, tid);
  }
}

// ---------------- conv: R6 structure + counted-vmcnt pipelined staging (T4) ----------------
// 256x128 C tile, 256 threads = 4 waves, wave tile 128x64, 16x16x32 MFMA — reads,
// MFMA, epilogue byte-identical to verified R6 (163 us). ONLY change: the per-step
// __syncthreads (which drains vmcnt(0) 144x) is replaced by {WAITVM(counted);
// s_barrier} at step top. A is TRI-buffered with depth-2 prefetch: stage A(s+2)
// after the barrier; WAITVM(4) leaves A(s+1)'s 4 loads/wave in flight across the
// barrier at 128/144 steps (m218 counted-vs-drain0 = +38-73%). B single-buffered,
// restaged behind a plain mid-step barrier at cg boundaries (Bs reads retired by
// MFMA lgkm waits before arrival). Per-wave FIFO: 4 A-loads/step; B (4-5) issued
// at t==8 AFTER A(s+1) -> t==0 must drain to 0 (confirms B); s==1/s==143 drain
// to 0 (no newer loads exist). Cross-wave visibility: own WAITVM precedes the
// rendezvous barrier — same contract as __syncthreads minus the flush.
__global__ __launch_bounds__(256, 2) void conv_mfma(
    const u16* __restrict__ Wmod, const u16* __restrict__ xt,
    float* __restrict__ out, int b0, int nb)
{
  const int id = blockIdx.x;
  const int bl = id % nb;                           // same batch -> same XCD (round robin)
  const int rest = id / nb;
  const int og = rest & 1, p_blk = rest >> 1;       // og: 256-row M chunk; p_blk: 128 px
  const int tid = threadIdx.x;
  const int lane = tid & 63, wave = tid >> 6;
  const int wm_off = (wave & 1) * 128, wn_off = (wave >> 1) * 64;
  const int l15 = lane & 15, quad = lane >> 4;

  __shared__ __align__(16) u16 As[3][8192];         // 3 x 16 KB A k-slices (tri-buffer)
  __shared__ __align__(16) u16 Bs[8448];            // [r4][col66][c32] = 16896 B

  const int y0 = p_blk * 2;
  const size_t xt_base = ((size_t)(bl * 16) * XT_CGELEMS) + (size_t)y0 * XT_ROWELEMS;
  const size_t w_base = (size_t)bl * WM_ELEMS + (size_t)og * (256 * 32);

  auto stage_b = [&](int cgi) {                     // 16896 B contiguous, async
    const char* g = (const char*)(xt + xt_base + (size_t)cgi * XT_CGELEMS);
    for (int r = wave; r < 16; r += 4)              // 4 GLDS/wave
      GLDS(g + r * 1024 + lane * 16, (char*)Bs + r * 1024);
    if (wave == 0 && lane < 32)                     // 512 B tail (wave0: 5th load)
      GLDS(g + 16384 + lane * 16, (char*)Bs + 16384);
  };
  auto stage_a = [&](int t, int cgi, int buf) {     // 16 KB contiguous, 4 GLDS/wave
    const char* g = (const char*)(Wmod + w_base + (size_t)(t * 16 + cgi) * 16384);
    for (int r = wave; r < 16; r += 4)
      GLDS(g + r * 1024 + lane * 16, (char*)As[buf] + r * 1024);
  };

  // loop-invariant swizzled fragment addresses (verified; conflicts = 0)
  int aoff[8];
#pragma unroll
  for (int mt = 0; mt < 8; ++mt) {
    int row = wm_off + mt * 16 + l15;               // local o-row; global o = og*256+row
    aoff[mt] = row * 32 + ((quad ^ ((row >> 1) & 3)) << 3);
  }
  int pr[4], pc[4];
#pragma unroll
  for (int nt = 0; nt < 4; ++nt) {
    int p = wn_off + nt * 16 + l15;
    pr[nt] = p >> 6; pc[nt] = p & 63;
  }

  floatx4 acc[8][4];
  const floatx4 zf = {0.f, 0.f, 0.f, 0.f};
#pragma unroll
  for (int mt = 0; mt < 8; ++mt)
#pragma unroll
    for (int nt = 0; nt < 4; ++nt) acc[mt][nt] = zf;

  // prologue: B(0) then A(s=0)->buf0 then A(s=1)->buf1; WAITVM(4) leaves A(1) in flight
  stage_b(0);
  stage_a(0, 0, 0);
  stage_a(1, 0, 1);
  WAITVM(4);
  __builtin_amdgcn_s_barrier();
  __builtin_amdgcn_sched_barrier(0);

#pragma unroll 1
  for (int cgi = 0; cgi < 16; ++cgi) {
#pragma unroll
    for (int t = 0; t < 9; ++t) {
      const int s = cgi * 9 + t;
      const int cur = t % 3;                        // s%3 == t%3 (9 ≡ 0 mod 3)
      // ---- top of step: counted drain + rendezvous (s==0 handled by prologue) ----
      if (s > 0) {
        if (t == 0 || s == 1 || s == 143) { WAITVM(0); }  // confirm B(cg) / no-newer cases
        else                              { WAITVM(4); }  // A(s) done; A(s+1) stays in flight
        __builtin_amdgcn_s_barrier();
        __builtin_amdgcn_sched_barrier(0);
      }
      // ---- depth-2 A prefetch into buffer (s+2)%3 (write-after-read safe: its
      //      readers finished before barrier(s), which precedes this issue) ----
      if (s + 2 <= 143) {
        int t2 = t + 2, cg2 = cgi;
        if (t2 >= 9) { t2 -= 9; ++cg2; }
        stage_a(t2, cg2, (t + 2) % 3);
      }

      const int ky = t / 3, kx = t - ky * 3;
      s16x8 afr[8], bfr[4];
      const u16* Ab = As[cur];
#pragma unroll
      for (int nt = 0; nt < 4; ++nt) {              // B[n=lane&15][k=quad*8+j], swizzled
        int r = pr[nt] + ky, c = pc[nt] + kx;
        bfr[nt] = *(const s16x8*)&Bs[(r * 66 + c) * 32 + ((quad ^ ((c >> 1) & 3)) << 3)];
      }
#pragma unroll
      for (int mt = 0; mt < 8; ++mt)                // A[m=lane&15][k=quad*8+j], swizzled
        afr[mt] = *(const s16x8*)&Ab[aoff[mt]];
#pragma unroll
      for (int mt = 0; mt < 8; ++mt)
#pragma unroll
        for (int nt = 0; nt < 4; ++nt)
          acc[mt][nt] = __builtin_amdgcn_mfma_f32_16x16x32_bf16(
              afr[mt], bfr[nt], acc[mt][nt], 0, 0, 0);

      if (t == 8 && cgi < 15) {                     // cg boundary: restage Bs
        __builtin_amdgcn_s_barrier();               // all waves' Bs reads retired (lgkm
        __builtin_amdgcn_sched_barrier(0);          //  waits precede MFMAs precede here)
        stage_b(cgi + 1);                           // async; confirmed at next t==0 top
      }
    }
  }

  // epilogue: C/D layout col=lane&15, row=quad*4+reg (m89-verified)
  float* outp = out + ((size_t)(b0 + bl) * 512 + og * 256) * 4096 + p_blk * 128;
#pragma unroll
  for (int mt = 0; mt < 8; ++mt)
#pragma unroll
    for (int nt = 0; nt < 4; ++nt) {
      int n = wn_off + nt * 16 + l15;
#pragma unroll
      for (int r = 0; r < 4; ++r) {
        int m = wm_off + mt * 16 + quad * 4 + r;
        outp[(size_t)m * 4096 + n] = acc[mt][nt][r];
      }
    }
}

// ---------------- fallback: zero-workspace direct conv (known-PASS) ----------------
__global__ __launch_bounds__(256) void conv_direct(
    const float* __restrict__ fm, const float* __restrict__ style,
    const float* __restrict__ w, float* __restrict__ out)
{
  const int o = blockIdx.x, b = blockIdx.y, tid = threadIdx.x;
  __shared__ float swm[4608];
  __shared__ float red[4];
  const float gain = 0.014731391f;
  const float* wo = w + (size_t)o * 4608;
  const float* st = style + (size_t)b * 512;
  float ss = 0.f;
#pragma unroll
  for (int j = 0; j < 18; ++j) {
    int idx = j * 256 + tid;
    float v = wo[idx] * gain * st[idx / 9];
    swm[idx] = v;
    ss += v * v;
  }
#pragma unroll
  for (int off = 32; off > 0; off >>= 1) ss += __shfl_down(ss, off, 64);
  if ((tid & 63) == 0) red[tid >> 6] = ss;
  __syncthreads();
  const float sinv = rsqrtf(red[0] + red[1] + red[2] + red[3] + 1e-8f);

  const int y = tid >> 2, x0 = (tid & 3) * 16;
  float acc[16];
#pragma unroll
  for (int i = 0; i < 16; ++i) acc[i] = 0.f;
  const float* fb = fm + (size_t)b * 512 * 4096;
  for (int ci = 0; ci < 512; ++ci) {
    const float* fc = fb + (size_t)ci * 4096;
    const float* wr = swm + ci * 9;
#pragma unroll
    for (int ky = 0; ky < 3; ++ky) {
      int yy = y + ky - 1;
      if (yy < 0 || yy > 63) continue;
      const float* frow = fc + yy * 64;
#pragma unroll
      for (int kx = 0; kx < 3; ++kx) {
        float wv = wr[ky * 3 + kx];
#pragma unroll
        for (int i = 0; i < 16; ++i) {
          int xx = x0 + i + kx - 1;
          float xv = (xx >= 0 && xx < 64) ? frow[xx] : 0.f;
          acc[i] += wv * xv;
        }
      }
    }
  }
  float* op = out + ((size_t)b * 512 + o) * 4096 + y * 64 + x0;
#pragma unroll
  for (int i = 0; i < 16; ++i) op[i] = acc[i] * sinv;
}

extern "C" void kernel_launch(void* const* d_in, const int* in_sizes, int n_in,
                              void* d_out, int out_size, void* d_ws, size_t ws_size,
                              hipStream_t stream) {
  const float* fm = (const float*)d_in[0];     // (8,512,64,64) fp32
  const float* style = (const float*)d_in[1];  // (8,512) fp32
  const float* w = (const float*)d_in[2];      // (512,512,3,3) fp32
  float* out = (float*)d_out;                  // (8,512,64,64) fp32

  if (ws_size < XT_PB + WM_PB) {               // workspace too small: direct path
    conv_direct<<<dim3(512, 8), 256, 0, stream>>>(fm, style, w, out);
    return;
  }
  int nb = 8;
  while (nb > 1 && (size_t)nb * (XT_PB + WM_PB) > ws_size) nb >>= 1;

  u16* xt = (u16*)d_ws;
  u16* wmod = (u16*)((char*)d_ws + (size_t)nb * XT_PB);

  for (int b0 = 0; b0 < 8; b0 += nb) {
    prep_fused<<<dim3(1536 * nb), 256, 0, stream>>>(fm, w, style, xt, wmod, b0);
    conv_mfma<<<dim3(64 * nb), 256, 0, stream>>>(wmod, xt, out, b0, nb);
  }
}